// Round 2
// baseline (1052.222 us; speedup 1.0000x reference)
//
#include <hip/hip_runtime.h>
#include <hip/hip_bf16.h>

#define TT 8192      // tokens
#define DD 1024
#define EE 8
#define HH 4096
#define SLOTS 16384  // TT * K
#define SLOTSP (SLOTS + 256)
#define MAXRT2 (SLOTS / 256 + EE)  // 72 worst-case 256-row tiles

typedef __bf16 bf16x8 __attribute__((ext_vector_type(8)));
typedef float f32x4 __attribute__((ext_vector_type(4)));

__device__ __forceinline__ float bf2f(unsigned u) { return __uint_as_float(u << 16); }
__device__ __forceinline__ unsigned short f2bf(float f) {
  __hip_bfloat16 h = __float2bfloat16(f);
  return __builtin_bit_cast(unsigned short, h);
}

// ctrl layout (ints): [0..7]=cnt  [8..16]=off  [17..24]=cursor  [25..33]=rtp

// -------------------- router: LN stats + logits + top2 --------------------
__global__ __launch_bounds__(256) void k_router(
    const float* __restrict__ x, const float* __restrict__ rls,
    const float* __restrict__ rlb, const float* __restrict__ rw,
    const float* __restrict__ rb, unsigned short* __restrict__ xhat,
    int* __restrict__ ctrl, int* __restrict__ topk, float* __restrict__ gates) {
  const int t = blockIdx.x, tid = threadIdx.x;
  const int lane = tid & 63, wave = tid >> 6;
  float4 v = ((const float4*)(x + (size_t)t * DD))[tid];
  float s = v.x + v.y + v.z + v.w;
  float s2 = v.x * v.x + v.y * v.y + v.z * v.z + v.w * v.w;
#pragma unroll
  for (int o = 32; o > 0; o >>= 1) { s += __shfl_down(s, o); s2 += __shfl_down(s2, o); }
  __shared__ float rs[4], rs2[4];
  if (lane == 0) { rs[wave] = s; rs2[wave] = s2; }
  __syncthreads();
  float ts = rs[0] + rs[1] + rs[2] + rs[3];
  float ts2 = rs2[0] + rs2[1] + rs2[2] + rs2[3];
  float mean = ts * (1.0f / DD);
  float var = ts2 * (1.0f / DD) - mean * mean;
  float inv = rsqrtf(var + 1e-6f);
  float xh0 = (v.x - mean) * inv, xh1 = (v.y - mean) * inv;
  float xh2 = (v.z - mean) * inv, xh3 = (v.w - mean) * inv;
  ushort4 pk;
  pk.x = f2bf(xh0); pk.y = f2bf(xh1); pk.z = f2bf(xh2); pk.w = f2bf(xh3);
  ((ushort4*)(xhat + (size_t)t * DD))[tid] = pk;
  float4 sc = ((const float4*)rls)[tid];
  float4 bi = ((const float4*)rlb)[tid];
  float r0 = fmaf(xh0, sc.x, bi.x), r1 = fmaf(xh1, sc.y, bi.y);
  float r2 = fmaf(xh2, sc.z, bi.z), r3 = fmaf(xh3, sc.w, bi.w);
  float pe[EE];
#pragma unroll
  for (int e = 0; e < EE; ++e) {
    float4 w = ((const float4*)(rw + (size_t)e * DD))[tid];
    pe[e] = fmaf(r0, w.x, fmaf(r1, w.y, fmaf(r2, w.z, r3 * w.w)));
  }
#pragma unroll
  for (int o = 32; o > 0; o >>= 1) {
#pragma unroll
    for (int e = 0; e < EE; ++e) pe[e] += __shfl_down(pe[e], o);
  }
  __shared__ float lred[4][EE];
  if (lane == 0) {
    for (int e = 0; e < EE; ++e) lred[wave][e] = pe[e];
  }
  __syncthreads();
  if (tid == 0) {
    float lg[EE];
    for (int e = 0; e < EE; ++e)
      lg[e] = lred[0][e] + lred[1][e] + lred[2][e] + lred[3][e] + rb[e];
    int i1 = 0;
    for (int e = 1; e < EE; ++e) if (lg[e] > lg[i1]) i1 = e;
    int i2 = -1;
    for (int e = 0; e < EE; ++e) { if (e == i1) continue; if (i2 < 0 || lg[e] > lg[i2]) i2 = e; }
    float eb = expf(lg[i2] - lg[i1]);
    float den = 1.0f / (1.0f + eb);
    topk[t] = i1 | (i2 << 8);
    gates[2 * t] = den;
    gates[2 * t + 1] = eb * den;
    atomicAdd(&ctrl[i1], 1);
    atomicAdd(&ctrl[i2], 1);
  }
}

// -------------------- offsets / cursors / row-tile prefix (256-row tiles) -------
__global__ void k_offsets(int* __restrict__ ctrl) {
  if (threadIdx.x == 0 && blockIdx.x == 0) {
    int o = 0, r = 0;
    ctrl[8] = 0; ctrl[25] = 0;
    for (int e = 0; e < EE; ++e) {
      int c = ctrl[e];
      ctrl[17 + e] = o;
      o += c;
      ctrl[9 + e] = o;
      r += (c + 255) >> 8;
      ctrl[26 + e] = r;
    }
  }
}

// -------------------- build A rows (expert LN applied to xhat) --------------------
__global__ __launch_bounds__(128) void k_build(
    const unsigned short* __restrict__ xhat, const float* __restrict__ els,
    const float* __restrict__ elb, int* __restrict__ ctrl,
    const int* __restrict__ topk, unsigned short* __restrict__ A,
    int* __restrict__ tok_pos) {
  int p = blockIdx.x, t = p >> 1, k = p & 1;
  __shared__ int sh[2];
  if (threadIdx.x == 0) {
    int e = (topk[t] >> (k * 8)) & 0xff;
    int pos = atomicAdd(&ctrl[17 + e], 1);
    tok_pos[p] = pos;
    sh[0] = e; sh[1] = pos;
  }
  __syncthreads();
  int e = sh[0], pos = sh[1];
  int i = threadIdx.x * 8;
  uint4 xv = *(const uint4*)(xhat + (size_t)t * DD + i);
  const float* sp = els + (size_t)e * DD + i;
  const float* bp = elb + (size_t)e * DD + i;
  float4 s0 = *(const float4*)sp, s1 = *(const float4*)(sp + 4);
  float4 b0 = *(const float4*)bp, b1 = *(const float4*)(bp + 4);
  unsigned r0 = (unsigned)f2bf(fmaf(bf2f(xv.x & 0xffffu), s0.x, b0.x)) |
                ((unsigned)f2bf(fmaf(bf2f(xv.x >> 16), s0.y, b0.y)) << 16);
  unsigned r1 = (unsigned)f2bf(fmaf(bf2f(xv.y & 0xffffu), s0.z, b0.z)) |
                ((unsigned)f2bf(fmaf(bf2f(xv.y >> 16), s0.w, b0.w)) << 16);
  unsigned r2 = (unsigned)f2bf(fmaf(bf2f(xv.z & 0xffffu), s1.x, b1.x)) |
                ((unsigned)f2bf(fmaf(bf2f(xv.z >> 16), s1.y, b1.y)) << 16);
  unsigned r3 = (unsigned)f2bf(fmaf(bf2f(xv.w & 0xffffu), s1.z, b1.z)) |
                ((unsigned)f2bf(fmaf(bf2f(xv.w >> 16), s1.w, b1.w)) << 16);
  uint4 ov; ov.x = r0; ov.y = r1; ov.z = r2; ov.w = r3;
  *(uint4*)(A + (size_t)pos * DD + i) = ov;
}

// -------------------- weights fp32 -> bf16 --------------------
__global__ __launch_bounds__(256) void k_wconv(
    const float* __restrict__ w1, const float* __restrict__ w2,
    unsigned short* __restrict__ w1b, unsigned short* __restrict__ w2b) {
  size_t i = (size_t)blockIdx.x * 256 + threadIdx.x;
  const size_t n4 = (size_t)EE * HH * DD / 4;
  const float4* src; unsigned short* dst; size_t j;
  if (i < n4) { src = (const float4*)w1; dst = w1b; j = i; }
  else        { src = (const float4*)w2; dst = w2b; j = i - n4; }
  float4 v = src[j];
  ushort4 ov;
  ov.x = f2bf(v.x); ov.y = f2bf(v.y); ov.z = f2bf(v.z); ov.w = f2bf(v.w);
  ((ushort4*)dst)[j] = ov;
}

// ---------- grouped GEMM, 256x256 tile, K-sliced deep pipeline (T1..T5) ----------
// LDS: 4 slice-pair buffers; buffer b: A-slice (256x32 bf16, 16KB) at b*32768,
// B-slice at b*32768+16384. Subtiled layout: subtile = 16 rows x 32 cols = 1024 B,
// index = row>>4; in-subtile byte = (row&15)*64 + col*2, XOR-swizzled:
// byte ^= ((byte>>9)&1)<<5 (st_16x32). Staged with linear global_load_lds dest +
// inverse-swizzled (same involution) per-lane global source.
#define STAGE(sl) { const int kk_ = (sl) * 32; const int bb_ = ((sl) & 3) << 15;   \
  __builtin_amdgcn_global_load_lds(                                                \
      (const __attribute__((address_space(1))) unsigned int*)(pa0 + kk_),          \
      (__attribute__((address_space(3))) unsigned int*)(lA0 + bb_), 16, 0, 0);     \
  __builtin_amdgcn_global_load_lds(                                                \
      (const __attribute__((address_space(1))) unsigned int*)(pa1 + kk_),          \
      (__attribute__((address_space(3))) unsigned int*)(lA1 + bb_), 16, 0, 0);     \
  __builtin_amdgcn_global_load_lds(                                                \
      (const __attribute__((address_space(1))) unsigned int*)(pb0 + kk_),          \
      (__attribute__((address_space(3))) unsigned int*)(lB0 + bb_), 16, 0, 0);     \
  __builtin_amdgcn_global_load_lds(                                                \
      (const __attribute__((address_space(1))) unsigned int*)(pb1 + kk_),          \
      (__attribute__((address_space(3))) unsigned int*)(lB1 + bb_), 16, 0, 0); }

template <int KDIM, bool GELU>
__global__ __launch_bounds__(512, 2) void k_gemm2(
    const unsigned short* __restrict__ Amat,  // [SLOTSP][KDIM] bf16
    const unsigned short* __restrict__ W,     // [EE][NTOT][KDIM] bf16
    const float* __restrict__ bias,           // [EE][NTOT]
    unsigned short* __restrict__ Outm,        // [SLOTSP][NTOT] bf16
    const int* __restrict__ ctrl, int NTOT) {
  constexpr int NS = KDIM / 32;  // k-slices
  __shared__ __align__(16) char smem[131072];
  const int* rtp = ctrl + 25;

  // bijective XCD swizzle (m204): consecutive lin2 on one XCD share the B panel
  const int nwg = gridDim.x * gridDim.y;
  const int lin = blockIdx.y * gridDim.x + blockIdx.x;
  const int xcd = lin & 7, loc = lin >> 3;
  const int q = nwg >> 3, rr = nwg & 7;
  const int lin2 = (xcd < rr ? xcd * (q + 1) : rr * (q + 1) + (xcd - rr) * q) + loc;
  const int bx = lin2 % gridDim.x;
  const int by = lin2 / gridDim.x;
  if (bx >= rtp[EE]) return;
  int e = 0;
  while (bx >= rtp[e + 1]) ++e;
  const int rt = bx - rtp[e];
  const int row0 = ctrl[8 + e] + rt * 256;
  int vrows = ctrl[e] - rt * 256;
  if (vrows > 256) vrows = 256;
  const int n0 = by * 256;

  const int tid = threadIdx.x, lane = tid & 63, w = tid >> 6;
  const int wr = w >> 2, wc = w & 3;  // 2M x 4N wave grid; per-wave out 128x64

  // staging lane geometry: lane l fills linear LDS bytes [16l,16l+16) of its
  // subtile; the element that belongs there is at swz(16l).
  const int u = (lane * 16) ^ (((lane >> 5) & 1) << 5);
  const int ri = u >> 6;         // 0..15 in-subtile row
  const int ci = (u & 63) >> 1;  // 0/8/16/24 in-subtile col
  const unsigned short* Ab = Amat + (size_t)row0 * KDIM;
  const unsigned short* Bb = W + ((size_t)e * NTOT + n0) * KDIM;
  const unsigned short* pa0 = Ab + (size_t)((w * 2 + 0) * 16 + ri) * KDIM + ci;
  const unsigned short* pa1 = Ab + (size_t)((w * 2 + 1) * 16 + ri) * KDIM + ci;
  const unsigned short* pb0 = Bb + (size_t)((w * 2 + 0) * 16 + ri) * KDIM + ci;
  const unsigned short* pb1 = Bb + (size_t)((w * 2 + 1) * 16 + ri) * KDIM + ci;
  char* lA0 = smem + (w * 2 + 0) * 1024;
  char* lA1 = smem + (w * 2 + 1) * 1024;
  char* lB0 = smem + 16384 + (w * 2 + 0) * 1024;
  char* lB1 = smem + 16384 + (w * 2 + 1) * 1024;

  // fragment-read lane term (swizzled): row=lane&15, col byte=(lane>>4)*16
  const int lt = (((lane & 15) << 6) | ((lane >> 4) << 4)) ^ (((lane >> 3) & 1) << 5);

  f32x4 acc[8][4];
#pragma unroll
  for (int m = 0; m < 8; ++m)
#pragma unroll
    for (int n = 0; n < 4; ++n) acc[m][n] = (f32x4){0.f, 0.f, 0.f, 0.f};

  // prologue: 3 slice-pairs in flight
  STAGE(0) STAGE(1) STAGE(2)

  for (int s = 0; s < NS; ++s) {
    if (s + 3 < NS) STAGE(s + 3)
    const int rem = NS - 1 - s;  // slice-pairs still (possibly) in flight
    if (rem >= 3)      asm volatile("s_waitcnt vmcnt(12)" ::: "memory");
    else if (rem == 2) asm volatile("s_waitcnt vmcnt(8)" ::: "memory");
    else if (rem == 1) asm volatile("s_waitcnt vmcnt(4)" ::: "memory");
    else               asm volatile("s_waitcnt vmcnt(0)" ::: "memory");
    asm volatile("s_barrier" ::: "memory");  // slice s landed for ALL waves
    const char* ab = smem + ((s & 3) << 15) + wr * 8192 + lt;
    const char* bb = smem + ((s & 3) << 15) + 16384 + wc * 4096 + lt;
    bf16x8 av[8], bv[4];
#pragma unroll
    for (int m = 0; m < 8; ++m) av[m] = *(const bf16x8*)(ab + m * 1024);
#pragma unroll
    for (int n = 0; n < 4; ++n) bv[n] = *(const bf16x8*)(bb + n * 1024);
    __builtin_amdgcn_s_setprio(1);
#pragma unroll
    for (int m = 0; m < 8; ++m)
#pragma unroll
      for (int n = 0; n < 4; ++n)
        acc[m][n] = __builtin_amdgcn_mfma_f32_16x16x32_bf16(av[m], bv[n], acc[m][n], 0, 0, 0);
    __builtin_amdgcn_s_setprio(0);
    asm volatile("s_barrier" ::: "memory");  // all reads of slice s done before anyone stages s+4
  }

#pragma unroll
  for (int m = 0; m < 8; ++m) {
    const int rb_ = wr * 128 + m * 16 + (lane >> 4) * 4;
#pragma unroll
    for (int n = 0; n < 4; ++n) {
      const int col = n0 + wc * 64 + n * 16 + (lane & 15);
      const float bv_ = bias[(size_t)e * NTOT + col];
#pragma unroll
      for (int j = 0; j < 4; ++j) {
        const int r = rb_ + j;
        if (r < vrows) {
          float vv = acc[m][n][j] + bv_;
          if constexpr (GELU) vv = 0.5f * vv * (1.0f + erff(vv * 0.70710678f));
          Outm[(size_t)(row0 + r) * NTOT + col] = f2bf(vv);
        }
      }
    }
  }
}

// -------------------- combine: out[t] = g0*Y[p0] + g1*Y[p1] --------------------
__global__ __launch_bounds__(256) void k_combine(
    const unsigned short* __restrict__ Y, const int* __restrict__ tok_pos,
    const float* __restrict__ gates, float* __restrict__ out) {
  int t = blockIdx.x, tid = threadIdx.x;
  int p0 = tok_pos[2 * t], p1 = tok_pos[2 * t + 1];
  float g0 = gates[2 * t], g1 = gates[2 * t + 1];
  ushort4 y0 = ((const ushort4*)(Y + (size_t)p0 * DD))[tid];
  ushort4 y1 = ((const ushort4*)(Y + (size_t)p1 * DD))[tid];
  float4 o;
  o.x = g0 * bf2f(y0.x) + g1 * bf2f(y1.x);
  o.y = g0 * bf2f(y0.y) + g1 * bf2f(y1.y);
  o.z = g0 * bf2f(y0.z) + g1 * bf2f(y1.z);
  o.w = g0 * bf2f(y0.w) + g1 * bf2f(y1.w);
  ((float4*)(out + (size_t)t * DD))[tid] = o;
}

__global__ __launch_bounds__(256) void k_sentinel(float* out, int n) {
  int i = blockIdx.x * 256 + threadIdx.x;
  if (i < n) out[i] = 12345.0f;
}

extern "C" void kernel_launch(void* const* d_in, const int* in_sizes, int n_in,
                              void* d_out, int out_size, void* d_ws, size_t ws_size,
                              hipStream_t stream) {
  const float* x   = (const float*)d_in[0];
  const float* rls = (const float*)d_in[1];
  const float* rlb = (const float*)d_in[2];
  const float* rw  = (const float*)d_in[3];
  const float* rb  = (const float*)d_in[4];
  const float* els = (const float*)d_in[5];
  const float* elb = (const float*)d_in[6];
  const float* w1  = (const float*)d_in[7];
  const float* b1  = (const float*)d_in[8];
  const float* w2  = (const float*)d_in[9];
  const float* b2  = (const float*)d_in[10];
  float* out = (float*)d_out;

  char* wsb = (char*)d_ws;
  size_t o = 0;
  int* ctrl = (int*)(wsb + o);                    o += 256;
  int* tok_pos = (int*)(wsb + o);                 o += (size_t)SLOTS * 4;
  float* gates = (float*)(wsb + o);               o += (size_t)SLOTS * 4;
  int* topk = (int*)(wsb + o);                    o += (size_t)TT * 4;
  unsigned short* xhat = (unsigned short*)(wsb + o); o += (size_t)TT * DD * 2;
  unsigned short* Abuf = (unsigned short*)(wsb + o); o += (size_t)SLOTSP * DD * 2;
  unsigned short* w1b = (unsigned short*)(wsb + o);  o += (size_t)EE * HH * DD * 2;
  unsigned short* w2b = (unsigned short*)(wsb + o);  o += (size_t)EE * DD * HH * 2;
  unsigned short* Hm = (unsigned short*)(wsb + o);   o += (size_t)SLOTSP * HH * 2;
  unsigned short* Yb = (unsigned short*)(wsb + o);   o += (size_t)SLOTS * DD * 2;

  if (ws_size < o) {
    k_sentinel<<<(out_size + 255) / 256, 256, 0, stream>>>(out, out_size);
    return;
  }

  hipMemsetAsync(ctrl, 0, 256, stream);
  k_router<<<TT, 256, 0, stream>>>(x, rls, rlb, rw, rb, xhat, ctrl, topk, gates);
  k_wconv<<<65536, 256, 0, stream>>>(w1, w2, w1b, w2b);
  k_offsets<<<1, 64, 0, stream>>>(ctrl);
  k_build<<<SLOTS, 128, 0, stream>>>(xhat, els, elb, ctrl, topk, Abuf, tok_pos);
  k_gemm2<DD, true><<<dim3(MAXRT2, HH / 256), 512, 0, stream>>>(Abuf, w1b, b1, Hm, ctrl, HH);
  k_gemm2<HH, false><<<dim3(MAXRT2, DD / 256), 512, 0, stream>>>(Hm, w2b, b2, Yb, ctrl, DD);
  k_combine<<<TT, 256, 0, stream>>>(Yb, tok_pos, gates, out);
}

// Round 3
// 1019.945 us; speedup vs baseline: 1.0316x; 1.0316x over previous
//
#include <hip/hip_runtime.h>
#include <hip/hip_bf16.h>

#define TT 8192      // tokens
#define DD 1024
#define EE 8
#define HH 4096
#define SLOTS 16384  // TT * K
#define SLOTSP (SLOTS + 256)
#define MAXRT2 (SLOTS / 256 + EE)  // 72 worst-case 256-row tiles

typedef __bf16 bf16x8 __attribute__((ext_vector_type(8)));
typedef float f32x4 __attribute__((ext_vector_type(4)));

__device__ __forceinline__ float bf2f(unsigned u) { return __uint_as_float(u << 16); }
__device__ __forceinline__ unsigned short f2bf(float f) {
  __hip_bfloat16 h = __float2bfloat16(f);
  return __builtin_bit_cast(unsigned short, h);
}

// ctrl layout (ints): [0..7]=cnt  [8..16]=off  [17..24]=cursor  [25..33]=rtp

// -------------------- router: LN stats + logits + top2 --------------------
__global__ __launch_bounds__(256) void k_router(
    const float* __restrict__ x, const float* __restrict__ rls,
    const float* __restrict__ rlb, const float* __restrict__ rw,
    const float* __restrict__ rb, unsigned short* __restrict__ xhat,
    int* __restrict__ ctrl, int* __restrict__ topk, float* __restrict__ gates) {
  const int t = blockIdx.x, tid = threadIdx.x;
  const int lane = tid & 63, wave = tid >> 6;
  float4 v = ((const float4*)(x + (size_t)t * DD))[tid];
  float s = v.x + v.y + v.z + v.w;
  float s2 = v.x * v.x + v.y * v.y + v.z * v.z + v.w * v.w;
#pragma unroll
  for (int o = 32; o > 0; o >>= 1) { s += __shfl_down(s, o); s2 += __shfl_down(s2, o); }
  __shared__ float rs[4], rs2[4];
  if (lane == 0) { rs[wave] = s; rs2[wave] = s2; }
  __syncthreads();
  float ts = rs[0] + rs[1] + rs[2] + rs[3];
  float ts2 = rs2[0] + rs2[1] + rs2[2] + rs2[3];
  float mean = ts * (1.0f / DD);
  float var = ts2 * (1.0f / DD) - mean * mean;
  float inv = rsqrtf(var + 1e-6f);
  float xh0 = (v.x - mean) * inv, xh1 = (v.y - mean) * inv;
  float xh2 = (v.z - mean) * inv, xh3 = (v.w - mean) * inv;
  ushort4 pk;
  pk.x = f2bf(xh0); pk.y = f2bf(xh1); pk.z = f2bf(xh2); pk.w = f2bf(xh3);
  ((ushort4*)(xhat + (size_t)t * DD))[tid] = pk;
  float4 sc = ((const float4*)rls)[tid];
  float4 bi = ((const float4*)rlb)[tid];
  float r0 = fmaf(xh0, sc.x, bi.x), r1 = fmaf(xh1, sc.y, bi.y);
  float r2 = fmaf(xh2, sc.z, bi.z), r3 = fmaf(xh3, sc.w, bi.w);
  float pe[EE];
#pragma unroll
  for (int e = 0; e < EE; ++e) {
    float4 w = ((const float4*)(rw + (size_t)e * DD))[tid];
    pe[e] = fmaf(r0, w.x, fmaf(r1, w.y, fmaf(r2, w.z, r3 * w.w)));
  }
#pragma unroll
  for (int o = 32; o > 0; o >>= 1) {
#pragma unroll
    for (int e = 0; e < EE; ++e) pe[e] += __shfl_down(pe[e], o);
  }
  __shared__ float lred[4][EE];
  if (lane == 0) {
    for (int e = 0; e < EE; ++e) lred[wave][e] = pe[e];
  }
  __syncthreads();
  if (tid == 0) {
    float lg[EE];
    for (int e = 0; e < EE; ++e)
      lg[e] = lred[0][e] + lred[1][e] + lred[2][e] + lred[3][e] + rb[e];
    int i1 = 0;
    for (int e = 1; e < EE; ++e) if (lg[e] > lg[i1]) i1 = e;
    int i2 = -1;
    for (int e = 0; e < EE; ++e) { if (e == i1) continue; if (i2 < 0 || lg[e] > lg[i2]) i2 = e; }
    float eb = expf(lg[i2] - lg[i1]);
    float den = 1.0f / (1.0f + eb);
    topk[t] = i1 | (i2 << 8);
    gates[2 * t] = den;
    gates[2 * t + 1] = eb * den;
    atomicAdd(&ctrl[i1], 1);
    atomicAdd(&ctrl[i2], 1);
  }
}

// -------------------- offsets / cursors / row-tile prefix (256-row tiles) -------
__global__ void k_offsets(int* __restrict__ ctrl) {
  if (threadIdx.x == 0 && blockIdx.x == 0) {
    int o = 0, r = 0;
    ctrl[8] = 0; ctrl[25] = 0;
    for (int e = 0; e < EE; ++e) {
      int c = ctrl[e];
      ctrl[17 + e] = o;
      o += c;
      ctrl[9 + e] = o;
      r += (c + 255) >> 8;
      ctrl[26 + e] = r;
    }
  }
}

// -------------------- build A rows (expert LN applied to xhat) --------------------
__global__ __launch_bounds__(128) void k_build(
    const unsigned short* __restrict__ xhat, const float* __restrict__ els,
    const float* __restrict__ elb, int* __restrict__ ctrl,
    const int* __restrict__ topk, unsigned short* __restrict__ A,
    int* __restrict__ tok_pos) {
  int p = blockIdx.x, t = p >> 1, k = p & 1;
  __shared__ int sh[2];
  if (threadIdx.x == 0) {
    int e = (topk[t] >> (k * 8)) & 0xff;
    int pos = atomicAdd(&ctrl[17 + e], 1);
    tok_pos[p] = pos;
    sh[0] = e; sh[1] = pos;
  }
  __syncthreads();
  int e = sh[0], pos = sh[1];
  int i = threadIdx.x * 8;
  uint4 xv = *(const uint4*)(xhat + (size_t)t * DD + i);
  const float* sp = els + (size_t)e * DD + i;
  const float* bp = elb + (size_t)e * DD + i;
  float4 s0 = *(const float4*)sp, s1 = *(const float4*)(sp + 4);
  float4 b0 = *(const float4*)bp, b1 = *(const float4*)(bp + 4);
  unsigned r0 = (unsigned)f2bf(fmaf(bf2f(xv.x & 0xffffu), s0.x, b0.x)) |
                ((unsigned)f2bf(fmaf(bf2f(xv.x >> 16), s0.y, b0.y)) << 16);
  unsigned r1 = (unsigned)f2bf(fmaf(bf2f(xv.y & 0xffffu), s0.z, b0.z)) |
                ((unsigned)f2bf(fmaf(bf2f(xv.y >> 16), s0.w, b0.w)) << 16);
  unsigned r2 = (unsigned)f2bf(fmaf(bf2f(xv.z & 0xffffu), s1.x, b1.x)) |
                ((unsigned)f2bf(fmaf(bf2f(xv.z >> 16), s1.y, b1.y)) << 16);
  unsigned r3 = (unsigned)f2bf(fmaf(bf2f(xv.w & 0xffffu), s1.z, b1.z)) |
                ((unsigned)f2bf(fmaf(bf2f(xv.w >> 16), s1.w, b1.w)) << 16);
  uint4 ov; ov.x = r0; ov.y = r1; ov.z = r2; ov.w = r3;
  *(uint4*)(A + (size_t)pos * DD + i) = ov;
}

// -------------------- weights fp32 -> bf16 --------------------
__global__ __launch_bounds__(256) void k_wconv(
    const float* __restrict__ w1, const float* __restrict__ w2,
    unsigned short* __restrict__ w1b, unsigned short* __restrict__ w2b) {
  size_t i = (size_t)blockIdx.x * 256 + threadIdx.x;
  const size_t n4 = (size_t)EE * HH * DD / 4;
  const float4* src; unsigned short* dst; size_t j;
  if (i < n4) { src = (const float4*)w1; dst = w1b; j = i; }
  else        { src = (const float4*)w2; dst = w2b; j = i - n4; }
  float4 v = src[j];
  ushort4 ov;
  ov.x = f2bf(v.x); ov.y = f2bf(v.y); ov.z = f2bf(v.z); ov.w = f2bf(v.w);
  ((ushort4*)dst)[j] = ov;
}

// ---------- grouped GEMM, 256x256 tile, K-sliced software-pipelined ----------
// LDS: 4 slice-pair buffers; buffer b: A-slice (256x32 bf16, 16KB) at b*32768,
// B-slice at b*32768+16384. st_16x32 XOR swizzle (byte ^= ((byte>>9)&1)<<5),
// staged via linear global_load_lds dest + inverse-swizzled per-lane source.
//
// Pipeline (iter s): STAGE(s+3) | vmcnt(8): slice s+1 landed (own wave)
//  | lgkmcnt(0): my frag reads from iter s-1 complete | s_barrier: cross-wave
//  visibility of slice s+1 AND all waves' frag(s) reads done | ds_read
//  frag(s+1) | 32 MFMA on frag(s) regs.  LDS latency hides under MFMAs.
// WAR proof: STAGE(s+3) writes buf[(s-1)&3]; frag(s-1) reads were issued in
// iter s-2 and completed by every wave's lgkmcnt(0) in iter s-1, which is
// before barrier_{s-1}; STAGE(s+3) is after barrier_{s-1}. Safe.
// RAW proof: slice s+1 staged at iter s-2; own-wave vmcnt(8) at iter s ensures
// landing; barrier_s publishes cross-wave before frag(s+1) reads. Safe.
#define STAGE(sl) { const int kk_ = (sl) * 32; const int bb_ = ((sl) & 3) << 15;   \
  __builtin_amdgcn_global_load_lds(                                                \
      (const __attribute__((address_space(1))) unsigned int*)(pa0 + kk_),          \
      (__attribute__((address_space(3))) unsigned int*)(lA0 + bb_), 16, 0, 0);     \
  __builtin_amdgcn_global_load_lds(                                                \
      (const __attribute__((address_space(1))) unsigned int*)(pa1 + kk_),          \
      (__attribute__((address_space(3))) unsigned int*)(lA1 + bb_), 16, 0, 0);     \
  __builtin_amdgcn_global_load_lds(                                                \
      (const __attribute__((address_space(1))) unsigned int*)(pb0 + kk_),          \
      (__attribute__((address_space(3))) unsigned int*)(lB0 + bb_), 16, 0, 0);     \
  __builtin_amdgcn_global_load_lds(                                                \
      (const __attribute__((address_space(1))) unsigned int*)(pb1 + kk_),          \
      (__attribute__((address_space(3))) unsigned int*)(lB1 + bb_), 16, 0, 0); }

#define ITER(s, ra, rb, ca, cb)                                                \
  {                                                                            \
    if ((s) + 3 < NS) STAGE((s) + 3)                                           \
    if ((s) <= NS - 4)                                                         \
      asm volatile("s_waitcnt vmcnt(8)" ::: "memory");                         \
    else if ((s) == NS - 3)                                                    \
      asm volatile("s_waitcnt vmcnt(4)" ::: "memory");                         \
    else                                                                       \
      asm volatile("s_waitcnt vmcnt(0)" ::: "memory");                         \
    asm volatile("s_waitcnt lgkmcnt(0)" ::: "memory");                         \
    __builtin_amdgcn_s_barrier();                                              \
    asm volatile("" ::: "memory");                                             \
    const char* ab_ = smem + ((((s) + 1) & 3) << 15) + wr * 8192 + lt;         \
    const char* bb_ = smem + ((((s) + 1) & 3) << 15) + 16384 + wc * 4096 + lt; \
    _Pragma("unroll")                                                          \
    for (int m_ = 0; m_ < 8; ++m_) ra[m_] = *(const bf16x8*)(ab_ + m_ * 1024); \
    _Pragma("unroll")                                                          \
    for (int n_ = 0; n_ < 4; ++n_) rb[n_] = *(const bf16x8*)(bb_ + n_ * 1024); \
    __builtin_amdgcn_s_setprio(1);                                             \
    _Pragma("unroll")                                                          \
    for (int m_ = 0; m_ < 8; ++m_)                                             \
      _Pragma("unroll")                                                        \
      for (int n_ = 0; n_ < 4; ++n_)                                           \
        acc[m_][n_] = __builtin_amdgcn_mfma_f32_16x16x32_bf16(                 \
            ca[m_], cb[n_], acc[m_][n_], 0, 0, 0);                             \
    __builtin_amdgcn_s_setprio(0);                                             \
  }

template <int KDIM, bool GELU>
__global__ __launch_bounds__(512, 2) void k_gemm2(
    const unsigned short* __restrict__ Amat,  // [SLOTSP][KDIM] bf16
    const unsigned short* __restrict__ W,     // [EE][NTOT][KDIM] bf16
    const float* __restrict__ bias,           // [EE][NTOT]
    unsigned short* __restrict__ Outm,        // [SLOTSP][NTOT] bf16
    const int* __restrict__ ctrl, int NTOT) {
  constexpr int NS = KDIM / 32;  // k-slices (even)
  __shared__ __align__(16) char smem[131072];
  const int* rtp = ctrl + 25;

  // bijective XCD swizzle (m204)
  const int nwg = gridDim.x * gridDim.y;
  const int lin = blockIdx.y * gridDim.x + blockIdx.x;
  const int xcd = lin & 7, loc = lin >> 3;
  const int q = nwg >> 3, rr = nwg & 7;
  const int lin2 = (xcd < rr ? xcd * (q + 1) : rr * (q + 1) + (xcd - rr) * q) + loc;
  const int bx = lin2 % gridDim.x;
  const int by = lin2 / gridDim.x;
  if (bx >= rtp[EE]) return;
  int e = 0;
  while (bx >= rtp[e + 1]) ++e;
  const int rt = bx - rtp[e];
  const int row0 = ctrl[8 + e] + rt * 256;
  int vrows = ctrl[e] - rt * 256;
  if (vrows > 256) vrows = 256;
  const int n0 = by * 256;

  const int tid = threadIdx.x, lane = tid & 63, w = tid >> 6;
  const int wr = w >> 2, wc = w & 3;  // 2M x 4N waves; per-wave out 128x64

  // staging lane geometry (inverse swizzle on the global source)
  const int u = (lane * 16) ^ (((lane >> 5) & 1) << 5);
  const int ri = u >> 6;
  const int ci = (u & 63) >> 1;
  const unsigned short* Ab = Amat + (size_t)row0 * KDIM;
  const unsigned short* Bb = W + ((size_t)e * NTOT + n0) * KDIM;
  const unsigned short* pa0 = Ab + (size_t)((w * 2 + 0) * 16 + ri) * KDIM + ci;
  const unsigned short* pa1 = Ab + (size_t)((w * 2 + 1) * 16 + ri) * KDIM + ci;
  const unsigned short* pb0 = Bb + (size_t)((w * 2 + 0) * 16 + ri) * KDIM + ci;
  const unsigned short* pb1 = Bb + (size_t)((w * 2 + 1) * 16 + ri) * KDIM + ci;
  char* lA0 = smem + (w * 2 + 0) * 1024;
  char* lA1 = smem + (w * 2 + 1) * 1024;
  char* lB0 = smem + 16384 + (w * 2 + 0) * 1024;
  char* lB1 = smem + 16384 + (w * 2 + 1) * 1024;

  // fragment-read lane term (swizzled)
  const int lt = (((lane & 15) << 6) | ((lane >> 4) << 4)) ^ (((lane >> 3) & 1) << 5);

  f32x4 acc[8][4];
#pragma unroll
  for (int m = 0; m < 8; ++m)
#pragma unroll
    for (int n = 0; n < 4; ++n) acc[m][n] = (f32x4){0.f, 0.f, 0.f, 0.f};

  bf16x8 a0[8], b0[4], a1[8], b1[4];

  // prologue: 3 slice-pairs in flight; read frag 0 into set 0
  STAGE(0) STAGE(1) STAGE(2)
  asm volatile("s_waitcnt vmcnt(8)" ::: "memory");
  __builtin_amdgcn_s_barrier();
  asm volatile("" ::: "memory");
  {
    const char* ab_ = smem + wr * 8192 + lt;
    const char* bb_ = smem + 16384 + wc * 4096 + lt;
#pragma unroll
    for (int m = 0; m < 8; ++m) a0[m] = *(const bf16x8*)(ab_ + m * 1024);
#pragma unroll
    for (int n = 0; n < 4; ++n) b0[n] = *(const bf16x8*)(bb_ + n * 1024);
  }

  for (int s = 0; s < NS; s += 2) {
    ITER(s, a1, b1, a0, b0)       // read frag s+1 -> set1, MFMA frag s (set0)
    ITER(s + 1, a0, b0, a1, b1)   // read frag s+2 -> set0, MFMA frag s+1 (set1)
  }

#pragma unroll
  for (int m = 0; m < 8; ++m) {
    const int rb_ = wr * 128 + m * 16 + (lane >> 4) * 4;
#pragma unroll
    for (int n = 0; n < 4; ++n) {
      const int col = n0 + wc * 64 + n * 16 + (lane & 15);
      const float bv_ = bias[(size_t)e * NTOT + col];
#pragma unroll
      for (int j = 0; j < 4; ++j) {
        const int r = rb_ + j;
        if (r < vrows) {
          float vv = acc[m][n][j] + bv_;
          if constexpr (GELU) vv = 0.5f * vv * (1.0f + erff(vv * 0.70710678f));
          Outm[(size_t)(row0 + r) * NTOT + col] = f2bf(vv);
        }
      }
    }
  }
}

// -------------------- combine: out[t] = g0*Y[p0] + g1*Y[p1] --------------------
__global__ __launch_bounds__(256) void k_combine(
    const unsigned short* __restrict__ Y, const int* __restrict__ tok_pos,
    const float* __restrict__ gates, float* __restrict__ out) {
  int t = blockIdx.x, tid = threadIdx.x;
  int p0 = tok_pos[2 * t], p1 = tok_pos[2 * t + 1];
  float g0 = gates[2 * t], g1 = gates[2 * t + 1];
  ushort4 y0 = ((const ushort4*)(Y + (size_t)p0 * DD))[tid];
  ushort4 y1 = ((const ushort4*)(Y + (size_t)p1 * DD))[tid];
  float4 o;
  o.x = g0 * bf2f(y0.x) + g1 * bf2f(y1.x);
  o.y = g0 * bf2f(y0.y) + g1 * bf2f(y1.y);
  o.z = g0 * bf2f(y0.z) + g1 * bf2f(y1.z);
  o.w = g0 * bf2f(y0.w) + g1 * bf2f(y1.w);
  ((float4*)(out + (size_t)t * DD))[tid] = o;
}

__global__ __launch_bounds__(256) void k_sentinel(float* out, int n) {
  int i = blockIdx.x * 256 + threadIdx.x;
  if (i < n) out[i] = 12345.0f;
}

extern "C" void kernel_launch(void* const* d_in, const int* in_sizes, int n_in,
                              void* d_out, int out_size, void* d_ws, size_t ws_size,
                              hipStream_t stream) {
  const float* x   = (const float*)d_in[0];
  const float* rls = (const float*)d_in[1];
  const float* rlb = (const float*)d_in[2];
  const float* rw  = (const float*)d_in[3];
  const float* rb  = (const float*)d_in[4];
  const float* els = (const float*)d_in[5];
  const float* elb = (const float*)d_in[6];
  const float* w1  = (const float*)d_in[7];
  const float* b1  = (const float*)d_in[8];
  const float* w2  = (const float*)d_in[9];
  const float* b2  = (const float*)d_in[10];
  float* out = (float*)d_out;

  char* wsb = (char*)d_ws;
  size_t o = 0;
  int* ctrl = (int*)(wsb + o);                    o += 256;
  int* tok_pos = (int*)(wsb + o);                 o += (size_t)SLOTS * 4;
  float* gates = (float*)(wsb + o);               o += (size_t)SLOTS * 4;
  int* topk = (int*)(wsb + o);                    o += (size_t)TT * 4;
  unsigned short* xhat = (unsigned short*)(wsb + o); o += (size_t)TT * DD * 2;
  unsigned short* Abuf = (unsigned short*)(wsb + o); o += (size_t)SLOTSP * DD * 2;
  unsigned short* w1b = (unsigned short*)(wsb + o);  o += (size_t)EE * HH * DD * 2;
  unsigned short* w2b = (unsigned short*)(wsb + o);  o += (size_t)EE * DD * HH * 2;
  unsigned short* Hm = (unsigned short*)(wsb + o);   o += (size_t)SLOTSP * HH * 2;
  unsigned short* Yb = (unsigned short*)(wsb + o);   o += (size_t)SLOTS * DD * 2;

  if (ws_size < o) {
    k_sentinel<<<(out_size + 255) / 256, 256, 0, stream>>>(out, out_size);
    return;
  }

  hipMemsetAsync(ctrl, 0, 256, stream);
  k_router<<<TT, 256, 0, stream>>>(x, rls, rlb, rw, rb, xhat, ctrl, topk, gates);
  k_wconv<<<65536, 256, 0, stream>>>(w1, w2, w1b, w2b);
  k_offsets<<<1, 64, 0, stream>>>(ctrl);
  k_build<<<SLOTS, 128, 0, stream>>>(xhat, els, elb, ctrl, topk, Abuf, tok_pos);
  k_gemm2<DD, true><<<dim3(MAXRT2, HH / 256), 512, 0, stream>>>(Abuf, w1b, b1, Hm, ctrl, HH);
  k_gemm2<HH, false><<<dim3(MAXRT2, DD / 256), 512, 0, stream>>>(Hm, w2b, b2, Yb, ctrl, DD);
  k_combine<<<TT, 256, 0, stream>>>(Yb, tok_pos, gates, out);
}

// Round 4
// 817.362 us; speedup vs baseline: 1.2873x; 1.2478x over previous
//
#include <hip/hip_runtime.h>
#include <hip/hip_bf16.h>

#define TT 8192      // tokens
#define DD 1024
#define EE 8
#define HH 4096
#define SLOTS 16384  // TT * K
#define SLOTSP (SLOTS + 256)
#define MAXRT2 (SLOTS / 256 + EE)  // 72 worst-case 256-row tiles

typedef __bf16 bf16x8 __attribute__((ext_vector_type(8)));
typedef float f32x4 __attribute__((ext_vector_type(4)));

__device__ __forceinline__ float bf2f(unsigned u) { return __uint_as_float(u << 16); }
__device__ __forceinline__ unsigned short f2bf(float f) {
  __hip_bfloat16 h = __float2bfloat16(f);
  return __builtin_bit_cast(unsigned short, h);
}
__device__ __forceinline__ f32x4 MF(bf16x8 a, bf16x8 b, f32x4 c) {
  return __builtin_amdgcn_mfma_f32_16x16x32_bf16(a, b, c, 0, 0, 0);
}

// ctrl layout (ints): [0..7]=cnt  [8..16]=off  [25..33]=rtp (256-row tiles)

// -------------------- router: LN stats + logits + top2 + ranks --------------------
__global__ __launch_bounds__(256) void k_router(
    const float* __restrict__ x, const float* __restrict__ rls,
    const float* __restrict__ rlb, const float* __restrict__ rw,
    const float* __restrict__ rb, unsigned short* __restrict__ xhat,
    int* __restrict__ ctrl, int* __restrict__ topk, float* __restrict__ gates,
    int* __restrict__ ranks) {
  const int t = blockIdx.x, tid = threadIdx.x;
  const int lane = tid & 63, wave = tid >> 6;
  float4 v = ((const float4*)(x + (size_t)t * DD))[tid];
  float s = v.x + v.y + v.z + v.w;
  float s2 = v.x * v.x + v.y * v.y + v.z * v.z + v.w * v.w;
#pragma unroll
  for (int o = 32; o > 0; o >>= 1) { s += __shfl_down(s, o); s2 += __shfl_down(s2, o); }
  __shared__ float rs[4], rs2[4];
  if (lane == 0) { rs[wave] = s; rs2[wave] = s2; }
  __syncthreads();
  float ts = rs[0] + rs[1] + rs[2] + rs[3];
  float ts2 = rs2[0] + rs2[1] + rs2[2] + rs2[3];
  float mean = ts * (1.0f / DD);
  float var = ts2 * (1.0f / DD) - mean * mean;
  float inv = rsqrtf(var + 1e-6f);
  float xh0 = (v.x - mean) * inv, xh1 = (v.y - mean) * inv;
  float xh2 = (v.z - mean) * inv, xh3 = (v.w - mean) * inv;
  ushort4 pk;
  pk.x = f2bf(xh0); pk.y = f2bf(xh1); pk.z = f2bf(xh2); pk.w = f2bf(xh3);
  ((ushort4*)(xhat + (size_t)t * DD))[tid] = pk;
  float4 sc = ((const float4*)rls)[tid];
  float4 bi = ((const float4*)rlb)[tid];
  float r0 = fmaf(xh0, sc.x, bi.x), r1 = fmaf(xh1, sc.y, bi.y);
  float r2 = fmaf(xh2, sc.z, bi.z), r3 = fmaf(xh3, sc.w, bi.w);
  float pe[EE];
#pragma unroll
  for (int e = 0; e < EE; ++e) {
    float4 w = ((const float4*)(rw + (size_t)e * DD))[tid];
    pe[e] = fmaf(r0, w.x, fmaf(r1, w.y, fmaf(r2, w.z, r3 * w.w)));
  }
#pragma unroll
  for (int o = 32; o > 0; o >>= 1) {
#pragma unroll
    for (int e = 0; e < EE; ++e) pe[e] += __shfl_down(pe[e], o);
  }
  __shared__ float lred[4][EE];
  if (lane == 0) {
    for (int e = 0; e < EE; ++e) lred[wave][e] = pe[e];
  }
  __syncthreads();
  if (tid == 0) {
    float lg[EE];
    for (int e = 0; e < EE; ++e)
      lg[e] = lred[0][e] + lred[1][e] + lred[2][e] + lred[3][e] + rb[e];
    int i1 = 0;
    for (int e = 1; e < EE; ++e) if (lg[e] > lg[i1]) i1 = e;
    int i2 = -1;
    for (int e = 0; e < EE; ++e) { if (e == i1) continue; if (i2 < 0 || lg[e] > lg[i2]) i2 = e; }
    float eb = expf(lg[i2] - lg[i1]);
    float den = 1.0f / (1.0f + eb);
    topk[t] = i1 | (i2 << 8);
    gates[2 * t] = den;
    gates[2 * t + 1] = eb * den;
    ranks[2 * t] = atomicAdd(&ctrl[i1], 1);
    ranks[2 * t + 1] = atomicAdd(&ctrl[i2], 1);
  }
}

// -------------------- offsets / row-tile prefix (256-row tiles) -------
__global__ void k_offsets(int* __restrict__ ctrl) {
  if (threadIdx.x == 0 && blockIdx.x == 0) {
    int o = 0, r = 0;
    ctrl[8] = 0; ctrl[25] = 0;
    for (int e = 0; e < EE; ++e) {
      int c = ctrl[e];
      o += c;
      ctrl[9 + e] = o;
      r += (c + 255) >> 8;
      ctrl[26 + e] = r;
    }
  }
}

// -------------------- build A rows (expert LN applied to xhat), no atomics ------
__global__ __launch_bounds__(128) void k_build(
    const unsigned short* __restrict__ xhat, const float* __restrict__ els,
    const float* __restrict__ elb, const int* __restrict__ ctrl,
    const int* __restrict__ topk, const int* __restrict__ ranks,
    unsigned short* __restrict__ A, int* __restrict__ tok_pos) {
  int p = blockIdx.x, t = p >> 1, k = p & 1;
  int e = (topk[t] >> (k * 8)) & 0xff;
  int pos = ctrl[8 + e] + ranks[p];
  if (threadIdx.x == 0) tok_pos[p] = pos;
  int i = threadIdx.x * 8;
  uint4 xv = *(const uint4*)(xhat + (size_t)t * DD + i);
  const float* sp = els + (size_t)e * DD + i;
  const float* bp = elb + (size_t)e * DD + i;
  float4 s0 = *(const float4*)sp, s1 = *(const float4*)(sp + 4);
  float4 b0 = *(const float4*)bp, b1 = *(const float4*)(bp + 4);
  unsigned r0 = (unsigned)f2bf(fmaf(bf2f(xv.x & 0xffffu), s0.x, b0.x)) |
                ((unsigned)f2bf(fmaf(bf2f(xv.x >> 16), s0.y, b0.y)) << 16);
  unsigned r1 = (unsigned)f2bf(fmaf(bf2f(xv.y & 0xffffu), s0.z, b0.z)) |
                ((unsigned)f2bf(fmaf(bf2f(xv.y >> 16), s0.w, b0.w)) << 16);
  unsigned r2 = (unsigned)f2bf(fmaf(bf2f(xv.z & 0xffffu), s1.x, b1.x)) |
                ((unsigned)f2bf(fmaf(bf2f(xv.z >> 16), s1.y, b1.y)) << 16);
  unsigned r3 = (unsigned)f2bf(fmaf(bf2f(xv.w & 0xffffu), s1.z, b1.z)) |
                ((unsigned)f2bf(fmaf(bf2f(xv.w >> 16), s1.w, b1.w)) << 16);
  uint4 ov; ov.x = r0; ov.y = r1; ov.z = r2; ov.w = r3;
  *(uint4*)(A + (size_t)pos * DD + i) = ov;
}

// -------------------- weights fp32 -> bf16 --------------------
__global__ __launch_bounds__(256) void k_wconv(
    const float* __restrict__ w1, const float* __restrict__ w2,
    unsigned short* __restrict__ w1b, unsigned short* __restrict__ w2b) {
  size_t i = (size_t)blockIdx.x * 256 + threadIdx.x;
  const size_t n4 = (size_t)EE * HH * DD / 4;
  const float4* src; unsigned short* dst; size_t j;
  if (i < n4) { src = (const float4*)w1; dst = w1b; j = i; }
  else        { src = (const float4*)w2; dst = w2b; j = i - n4; }
  float4 v = src[j];
  ushort4 ov;
  ov.x = f2bf(v.x); ov.y = f2bf(v.y); ov.z = f2bf(v.z); ov.w = f2bf(v.w);
  ((ushort4*)dst)[j] = ov;
}

// ============ grouped GEMM, 256x256 tile, BK=64, 8-phase schedule ============
// LDS 128KB: dbuf d (K-tile parity) at d*65536; within: A-half h at h*16384,
// B-half h at 32768+h*16384. Half = 128rx64c bf16 = 16 subtiles of 16rx32c
// (1KB). st_16x32 swizzle: in-subtile byte ^= ((row&8)?32:0); staged linear
// via inverse-swizzled per-lane global source. Per phase: {ds_reads | stage
// one half-tile (2 gl_lds/wave) | bar | lgkm0 | 16 MFMA | bar}. vmcnt(4) only
// at p3/p7. Stage ledger (iter i): p0:b1.A0(2i+1) p1:b1.B1(2i+1)
// p2:b0.B0(2i+2) p3:b0.A1 p4:b0.A0 p5:b0.B1 p6:b1.B0(2i+3) p7:b1.A1.
// Every slot re-staged >=1 phase after last read; every half lands >=3 phases
// + 1 barrier before first read (vmcnt(4)@p3 covers p0/p1; @p7 covers p4/p5).
#define GLL(S, D)                                                              \
  __builtin_amdgcn_global_load_lds(                                            \
      (const __attribute__((address_space(1))) unsigned int*)(S),              \
      (__attribute__((address_space(3))) unsigned int*)(D), 16, 0, 0)
#define STAGE_A(D, H, KT) do {                                                 \
    const unsigned short* s_ = pA + (size_t)(H) * 128 * KDIM + (KT) * 64;      \
    char* d_ = sL + (D) * 65536 + (H) * 16384;                                 \
    GLL(s_, d_); GLL(s_ + 32, d_ + 1024); } while (0)
#define STAGE_B(D, H, KT) do {                                                 \
    const unsigned short* s_ = pB + (size_t)(H) * 128 * KDIM + (KT) * 64;      \
    char* d_ = sL + (D) * 65536 + 32768 + (H) * 16384;                         \
    GLL(s_, d_); GLL(s_ + 32, d_ + 1024); } while (0)
#define RD_A(DST, D, GR) do {                                                  \
    const char* p_ = smem + (D) * 65536 + (GR) * 16384 + ((w >> 1) * 4) * 1024 + lt; \
    DST[0] = *(const bf16x8*)(p_);        DST[1] = *(const bf16x8*)(p_ + 1024);      \
    DST[2] = *(const bf16x8*)(p_ + 2048); DST[3] = *(const bf16x8*)(p_ + 3072); } while (0)
#define RD_B(DST, D, GC) do {                                                  \
    const char* p_ = smem + (D) * 65536 + 32768 + (GC) * 16384 + ((w & 1) * 8) * 1024 + lt; \
    _Pragma("unroll")                                                          \
    for (int q_ = 0; q_ < 8; ++q_) DST[q_] = *(const bf16x8*)(p_ + q_ * 1024); } while (0)
#define MM(QR, QC, AS, BS) do {                                                \
    _Pragma("unroll")                                                          \
    for (int m_ = 0; m_ < 2; ++m_)                                             \
      _Pragma("unroll")                                                        \
      for (int n_ = 0; n_ < 4; ++n_) {                                         \
        acc[QR][QC][m_][n_] = MF(AS[2 * m_], BS[2 * n_], acc[QR][QC][m_][n_]); \
        acc[QR][QC][m_][n_] = MF(AS[2 * m_ + 1], BS[2 * n_ + 1], acc[QR][QC][m_][n_]); \
      } } while (0)
#define BAR __builtin_amdgcn_s_barrier()
#define WLG0 asm volatile("s_waitcnt lgkmcnt(0)" ::: "memory")
#define WLG8 asm volatile("s_waitcnt lgkmcnt(8)" ::: "memory")
#define WVM4 asm volatile("s_waitcnt vmcnt(4)" ::: "memory")
#define SB0 __builtin_amdgcn_sched_barrier(0)
#define PRIO1 __builtin_amdgcn_s_setprio(1)
#define PRIO0 __builtin_amdgcn_s_setprio(0)

template <int KDIM, bool GELU>
__global__ __launch_bounds__(512, 2) void k_gemm2(
    const unsigned short* __restrict__ Amat,  // [SLOTSP][KDIM] bf16
    const unsigned short* __restrict__ W,     // [EE][NTOT][KDIM] bf16
    const float* __restrict__ bias,           // [EE][NTOT]
    unsigned short* __restrict__ Outm,        // [SLOTSP][NTOT] bf16
    const int* __restrict__ ctrl, int NTOT) {
  constexpr int NT = KDIM / 64;  // K-tiles (even, >=16)
  __shared__ __align__(16) char smem[131072];
  const int* rtp = ctrl + 25;

  // bijective XCD swizzle (m204)
  const int nwg = gridDim.x * gridDim.y;
  const int lin = blockIdx.y * gridDim.x + blockIdx.x;
  const int xcd = lin & 7, loc = lin >> 3;
  const int q = nwg >> 3, rr = nwg & 7;
  const int lin2 = (xcd < rr ? xcd * (q + 1) : rr * (q + 1) + (xcd - rr) * q) + loc;
  const int bx = lin2 % gridDim.x;
  const int by = lin2 / gridDim.x;
  if (bx >= rtp[EE]) return;
  int e = 0;
  while (bx >= rtp[e + 1]) ++e;
  const int rt = bx - rtp[e];
  const int row0 = ctrl[8 + e] + rt * 256;
  int vrows = ctrl[e] - rt * 256;
  if (vrows > 256) vrows = 256;
  const int n0 = by * 256;

  const int tid = threadIdx.x, lane = tid & 63, w = tid >> 6;

  // staging lane geometry (inverse swizzle on the global source)
  const int u = (lane * 16) ^ (((lane >> 5) & 1) << 5);
  const int ri = u >> 6;         // in-subtile row 0..15
  const int ci = (u & 63) >> 1;  // in-subtile col elem 0/8/16/24
  const unsigned short* Ab = Amat + (size_t)row0 * KDIM;
  const unsigned short* Bb = W + ((size_t)e * NTOT + n0) * KDIM;
  const unsigned short* pA = Ab + (size_t)(16 * w + ri) * KDIM + ci;
  const unsigned short* pB = Bb + (size_t)(16 * w + ri) * KDIM + ci;
  char* sL = smem + (2 * w) * 1024 + lane * 16;

  // fragment-read lane term (swizzled)
  const int lt = (((lane & 15) << 6) | ((lane >> 4) << 4)) ^ (((lane >> 3) & 1) << 5);

  f32x4 acc[2][2][2][4];
#pragma unroll
  for (int a_ = 0; a_ < 2; ++a_)
#pragma unroll
    for (int b_ = 0; b_ < 2; ++b_)
#pragma unroll
      for (int c_ = 0; c_ < 2; ++c_)
#pragma unroll
        for (int d_ = 0; d_ < 4; ++d_) acc[a_][b_][c_][d_] = (f32x4){0.f, 0.f, 0.f, 0.f};

  bf16x8 a0[4], a1[4], b[8];

  // prologue: buf0 all 4 halves (kt0), buf1 B0+A1 (kt1); 12 loads/wave
  STAGE_B(0, 0, 0); STAGE_A(0, 1, 0); STAGE_A(0, 0, 0); STAGE_B(0, 1, 0);
  STAGE_B(1, 0, 1); STAGE_A(1, 1, 1);
  WVM4;  // buf0's 8 loads landed
  BAR;

  for (int i = 0; i < NT / 2; ++i) {
    const int kt1 = 2 * i + 1;
    int kt2 = 2 * i + 2; if (kt2 >= NT) kt2 -= NT;  // wrapped prefetch (tail)
    int kt3 = 2 * i + 3; if (kt3 >= NT) kt3 -= NT;
    // ---- p0: K-tile 2i (buf0), quadrant (0,0)
    RD_A(a0, 0, 0); RD_B(b, 0, 0);
    STAGE_A(1, 0, kt1);
    WLG8; BAR; WLG0; SB0;
    PRIO1; MM(0, 0, a0, b); PRIO0;
    BAR;
    // ---- p1: quadrant (1,0)
    RD_A(a1, 0, 1);
    STAGE_B(1, 1, kt1);
    BAR; WLG0; SB0;
    PRIO1; MM(1, 0, a1, b); PRIO0;
    BAR;
    // ---- p2: quadrant (1,1)
    RD_B(b, 0, 1);
    STAGE_B(0, 0, kt2);
    BAR; WLG0; SB0;
    PRIO1; MM(1, 1, a1, b); PRIO0;
    BAR;
    // ---- p3: quadrant (0,1); counted vmcnt for buf1(kt1) halves
    STAGE_A(0, 1, kt2);
    WVM4; BAR; SB0;
    PRIO1; MM(0, 1, a0, b); PRIO0;
    BAR;
    // ---- p4: K-tile 2i+1 (buf1), quadrant (0,0)
    RD_A(a0, 1, 0); RD_B(b, 1, 0);
    STAGE_A(0, 0, kt2);
    WLG8; BAR; WLG0; SB0;
    PRIO1; MM(0, 0, a0, b); PRIO0;
    BAR;
    // ---- p5: quadrant (1,0)
    RD_A(a1, 1, 1);
    STAGE_B(0, 1, kt2);
    BAR; WLG0; SB0;
    PRIO1; MM(1, 0, a1, b); PRIO0;
    BAR;
    // ---- p6: quadrant (1,1)
    RD_B(b, 1, 1);
    STAGE_B(1, 0, kt3);
    BAR; WLG0; SB0;
    PRIO1; MM(1, 1, a1, b); PRIO0;
    BAR;
    // ---- p7: quadrant (0,1); counted vmcnt for buf0(kt2) halves
    STAGE_A(1, 1, kt3);
    WVM4; BAR; SB0;
    PRIO1; MM(0, 1, a0, b); PRIO0;
    BAR;
  }

  // epilogue: wave w piece in quadrant (qr,qc): rows (w>>1)*32+m*16, cols (w&1)*64+n*16
#pragma unroll
  for (int qr = 0; qr < 2; ++qr)
#pragma unroll
    for (int qc = 0; qc < 2; ++qc)
#pragma unroll
      for (int m = 0; m < 2; ++m)
#pragma unroll
        for (int n = 0; n < 4; ++n) {
          const int rbase = qr * 128 + (w >> 1) * 32 + m * 16 + (lane >> 4) * 4;
          const int col = n0 + qc * 128 + (w & 1) * 64 + n * 16 + (lane & 15);
          const float bv_ = bias[(size_t)e * NTOT + col];
#pragma unroll
          for (int j = 0; j < 4; ++j) {
            const int r = rbase + j;
            if (r < vrows) {
              float vv = acc[qr][qc][m][n][j] + bv_;
              if constexpr (GELU) vv = 0.5f * vv * (1.0f + erff(vv * 0.70710678f));
              Outm[(size_t)(row0 + r) * NTOT + col] = f2bf(vv);
            }
          }
        }
}

// -------------------- combine: out[t] = g0*Y[p0] + g1*Y[p1] --------------------
__global__ __launch_bounds__(256) void k_combine(
    const unsigned short* __restrict__ Y, const int* __restrict__ tok_pos,
    const float* __restrict__ gates, float* __restrict__ out) {
  int t = blockIdx.x, tid = threadIdx.x;
  int p0 = tok_pos[2 * t], p1 = tok_pos[2 * t + 1];
  float g0 = gates[2 * t], g1 = gates[2 * t + 1];
  ushort4 y0 = ((const ushort4*)(Y + (size_t)p0 * DD))[tid];
  ushort4 y1 = ((const ushort4*)(Y + (size_t)p1 * DD))[tid];
  float4 o;
  o.x = g0 * bf2f(y0.x) + g1 * bf2f(y1.x);
  o.y = g0 * bf2f(y0.y) + g1 * bf2f(y1.y);
  o.z = g0 * bf2f(y0.z) + g1 * bf2f(y1.z);
  o.w = g0 * bf2f(y0.w) + g1 * bf2f(y1.w);
  ((float4*)(out + (size_t)t * DD))[tid] = o;
}

__global__ __launch_bounds__(256) void k_sentinel(float* out, int n) {
  int i = blockIdx.x * 256 + threadIdx.x;
  if (i < n) out[i] = 12345.0f;
}

extern "C" void kernel_launch(void* const* d_in, const int* in_sizes, int n_in,
                              void* d_out, int out_size, void* d_ws, size_t ws_size,
                              hipStream_t stream) {
  const float* x   = (const float*)d_in[0];
  const float* rls = (const float*)d_in[1];
  const float* rlb = (const float*)d_in[2];
  const float* rw  = (const float*)d_in[3];
  const float* rb  = (const float*)d_in[4];
  const float* els = (const float*)d_in[5];
  const float* elb = (const float*)d_in[6];
  const float* w1  = (const float*)d_in[7];
  const float* b1  = (const float*)d_in[8];
  const float* w2  = (const float*)d_in[9];
  const float* b2  = (const float*)d_in[10];
  float* out = (float*)d_out;

  char* wsb = (char*)d_ws;
  size_t o = 0;
  int* ctrl = (int*)(wsb + o);                    o += 256;
  int* tok_pos = (int*)(wsb + o);                 o += (size_t)SLOTS * 4;
  float* gates = (float*)(wsb + o);               o += (size_t)SLOTS * 4;
  int* topk = (int*)(wsb + o);                    o += (size_t)TT * 4;
  int* ranks = (int*)(wsb + o);                   o += (size_t)SLOTS * 4;
  unsigned short* xhat = (unsigned short*)(wsb + o); o += (size_t)TT * DD * 2;
  unsigned short* Abuf = (unsigned short*)(wsb + o); o += (size_t)SLOTSP * DD * 2;
  unsigned short* w1b = (unsigned short*)(wsb + o);  o += (size_t)EE * HH * DD * 2;
  unsigned short* w2b = (unsigned short*)(wsb + o);  o += (size_t)EE * DD * HH * 2;
  unsigned short* Hm = (unsigned short*)(wsb + o);   o += (size_t)SLOTSP * HH * 2;
  unsigned short* Yb = (unsigned short*)(wsb + o);   o += (size_t)SLOTS * DD * 2;

  if (ws_size < o) {
    k_sentinel<<<(out_size + 255) / 256, 256, 0, stream>>>(out, out_size);
    return;
  }

  hipMemsetAsync(ctrl, 0, 256, stream);
  k_router<<<TT, 256, 0, stream>>>(x, rls, rlb, rw, rb, xhat, ctrl, topk, gates, ranks);
  k_wconv<<<65536, 256, 0, stream>>>(w1, w2, w1b, w2b);
  k_offsets<<<1, 64, 0, stream>>>(ctrl);
  k_build<<<SLOTS, 128, 0, stream>>>(xhat, els, elb, ctrl, topk, ranks, Abuf, tok_pos);
  k_gemm2<DD, true><<<dim3(MAXRT2, HH / 256), 512, 0, stream>>>(Abuf, w1b, b1, Hm, ctrl, HH);
  k_gemm2<HH, false><<<dim3(MAXRT2, DD / 256), 512, 0, stream>>>(Hm, w2b, b2, Yb, ctrl, DD);
  k_combine<<<TT, 256, 0, stream>>>(Yb, tok_pos, gates, out);
}